// Round 1
// baseline (312.280 us; speedup 1.0000x reference)
//
#include <hip/hip_runtime.h>
#include <math.h>

// Problem constants
#define C 256
#define K 1024
#define SS 4096          // 16*16*16 spatial
#define NB 8             // batch
#define NN 32768         // NB*SS rows
#define ZQ_ELEMS 8388608 // NB*C*SS
#define OUT_LOSS 8388608
#define OUT_PERP 8388609
#define OUT_IDX  8388610
#define OUT_MD   8421378

// workspace float layout
#define WS_SZ2   0       // sum z^2 (scalar)
#define WS_SE2   1       // sum e^2 (scalar)
#define WS_LOSS  2       // sum (zq-z)^2 (scalar)
#define WS_ZSUM  8       // [256] column sums of zf
#define WS_ESUM  264     // [256] column sums of emb
#define WS_CNT   520     // [1024] histogram (float)
#define WS_E2R   1544    // [1024] ||e_k||^2, numpy-pairwise f32
#define WS_Z2N   2568    // [32768] ||z_n||^2, numpy-pairwise f32
#define WS_FLG   35336   // int region: [0]=count, [1..NN]=rows
#define WS_EH    68608   // [1024*256] u16 emb-hi
#define WS_EL    199680  // [1024*256] u16 emb-lo
#define WS_PACK  330752  // [NN] u64 packed (key(d)<<32 | idx) per flag slot

#define T_FLAG 1.0e-4f

typedef __attribute__((ext_vector_type(8))) short short8;
typedef __attribute__((ext_vector_type(4))) float f32x4;
typedef unsigned short u16;
typedef unsigned long long u64;

__device__ inline u16 f2bf(float x) {  // f32 -> bf16 RNE
  unsigned u = __float_as_uint(x);
  unsigned r = (u + 0x7fffu + ((u >> 16) & 1u)) >> 16;
  return (u16)r;
}
__device__ inline float bf2f(u16 h) { return __uint_as_float(((unsigned)h) << 16); }

// ---- numpy pairwise f32 sum of squares, 256 contiguous elements ----
__device__ inline float np_sumsq_256(const float* __restrict__ a) {
  float tot = 0.f;
  #pragma unroll
  for (int h = 0; h < 2; ++h) {
    const float* p = a + 128 * h;
    float r[8];
    #pragma unroll
    for (int j = 0; j < 8; ++j) r[j] = __fmul_rn(p[j], p[j]);
    for (int i = 8; i < 128; i += 8) {
      #pragma unroll
      for (int j = 0; j < 8; ++j) {
        float v = p[i + j];
        r[j] = __fadd_rn(r[j], __fmul_rn(v, v));
      }
    }
    float s01 = __fadd_rn(r[0], r[1]);
    float s23 = __fadd_rn(r[2], r[3]);
    float s45 = __fadd_rn(r[4], r[5]);
    float s67 = __fadd_rn(r[6], r[7]);
    float res = __fadd_rn(__fadd_rn(s01, s23), __fadd_rn(s45, s67));
    tot = (h == 0) ? res : __fadd_rn(tot, res);
  }
  return tot;
}

// ---------- emb prep: split to eh/el, e2[k], col sums, Se2 ----------
__global__ __launch_bounds__(256)
void emb_prep_k(const float* __restrict__ emb, float* __restrict__ ws,
                u16* __restrict__ eh, u16* __restrict__ el) {
  int r0 = blockIdx.x * 16;   // 64 blocks x 16 rows
  int t = threadIdx.x;
  float s = 0.f;
  #pragma unroll
  for (int i = 0; i < 16; ++i) {
    size_t idx = (size_t)(r0 + i) * C + t;
    float v = emb[idx];
    s += v;
    u16 h = f2bf(v);
    eh[idx] = h;
    el[idx] = f2bf(v - bf2f(h));
  }
  atomicAdd(&ws[WS_ESUM + t], s);
  if (t < 16) {
    float e2 = np_sumsq_256(emb + (size_t)(r0 + t) * C);
    ws[WS_E2R + r0 + t] = e2;
    atomicAdd(&ws[WS_SE2], e2);
  }
}

#define MROWS 64
#define ZS_STRIDE 260

// ---------- one pass over z: zsum[c], Sz2, z2np[n], bf16 split zh/zl ----------
__global__ __launch_bounds__(256)
void prep_z_k(const float* __restrict__ z, float* __restrict__ ws,
              u16* __restrict__ zh_g, u16* __restrict__ zl_g) {
  __shared__ float zs[MROWS * ZS_STRIDE];
  const int t = threadIdx.x;
  const int n0 = blockIdx.x * MROWS;
  const int b = n0 / SS;
  const int s0 = n0 % SS;
  {
    const int sl = t & 63, cg = t >> 6;
    const float* zb = z + (size_t)b * C * SS + s0 + sl;
    #pragma unroll
    for (int i = 0; i < 16; ++i) {
      int c = (cg * 16 + i) * 4;
      float4 v;
      v.x = zb[(size_t)(c + 0) * SS];
      v.y = zb[(size_t)(c + 1) * SS];
      v.z = zb[(size_t)(c + 2) * SS];
      v.w = zb[(size_t)(c + 3) * SS];
      *(float4*)&zs[sl * ZS_STRIDE + c] = v;
    }
  }
  __syncthreads();
  // column sums
  {
    float s = 0.f;
    #pragma unroll 8
    for (int r = 0; r < MROWS; ++r) s += zs[r * ZS_STRIDE + t];
    atomicAdd(&ws[WS_ZSUM + t], s);
  }
  // bf16 split, lane-linear coalesced short8 stores
  {
    #pragma unroll
    for (int i = 0; i < 8; ++i) {
      int q = i * 256 + t;          // short8 chunk 0..2047
      int row = q >> 5;             // 0..63
      int c0 = (q & 31) * 8;
      float4 va = *(const float4*)&zs[row * ZS_STRIDE + c0];
      float4 vb = *(const float4*)&zs[row * ZS_STRIDE + c0 + 4];
      float f[8] = {va.x, va.y, va.z, va.w, vb.x, vb.y, vb.z, vb.w};
      short8 hv, lv;
      #pragma unroll
      for (int j = 0; j < 8; ++j) {
        u16 h = f2bf(f[j]);
        hv[j] = (short)h;
        lv[j] = (short)f2bf(f[j] - bf2f(h));
      }
      size_t off = (size_t)(n0 + row) * C + c0;
      *(short8*)&zh_g[off] = hv;
      *(short8*)&zl_g[off] = lv;
    }
  }
  // z2 (numpy-pairwise) + Sz2
  if (t < MROWS) {
    float z2 = np_sumsq_256(&zs[t * ZS_STRIDE]);
    ws[WS_Z2N + n0 + t] = z2;
    #pragma unroll
    for (int off = 32; off; off >>= 1) z2 += __shfl_down(z2, off);
    if (t == 0) atomicAdd(&ws[WS_SZ2], z2);
  }
}

// ---------- main: split-bf16 MFMA distances + top-2 argmin + flags ----------
// BM=64 -> grid 512 -> 2 blocks/CU co-resident (the R7 grid of 256 pinned
// occupancy at 1 block/CU and left every staging barrier latency-exposed).
// Waves 2x2: wave(wm,wn) = rows wm*32..+31 (mi 0..1) x cols wn*64..+63
// (ni 0..3). Col halves merged at the end via LDS. ~50 KB LDS.
#define BM 64
#define BN 128
#define CH 64

__global__ __launch_bounds__(256, 2)
void vq_mfma_k(const u16* __restrict__ zh_g, const u16* __restrict__ zl_g,
               const u16* __restrict__ eh_g, const u16* __restrict__ el_g,
               const float* __restrict__ e2row, float* __restrict__ out_idx,
               int* __restrict__ flags, u64* __restrict__ pack) {
  extern __shared__ u16 smem_u16[];
  u16* Ah = smem_u16;                 // [64][64] u16, swizzled
  u16* Al = Ah + BM * CH;
  u16* Bh = Al + BM * CH;             // [128][64]
  u16* Bl = Bh + BN * CH;
  float* e2s = (float*)(Bl + BN * CH);   // [128]
  float* mv1 = e2s + BN;              // [2][64] col-half merge
  float* mv2 = mv1 + 2 * BM;
  float* mi1 = mv2 + 2 * BM;

  const int t = threadIdx.x;
  const int lane = t & 63;
  const int wid = t >> 6;
  const int wm = wid >> 1, wn = wid & 1;
  const int quad = lane >> 4, lr = lane & 15;
  const int row0 = blockIdx.x * BM;

  // running top-2 per slot (mi*4 + r), cols restricted to this wave's half
  float v1[8], v2[8], i1f[8];
  #pragma unroll
  for (int s = 0; s < 8; ++s) { v1[s] = 3.4e38f; v2[s] = 3.4e38f; i1f[s] = 0.f; }

  for (int nt = 0; nt < K / BN; ++nt) {
    const int kc0 = nt * BN;
    __syncthreads();                 // prior n-tile's e2s readers done
    if (t < BN) e2s[t] = e2row[kc0 + t];

    f32x4 acc[2][4];
    #pragma unroll
    for (int mi = 0; mi < 2; ++mi)
      #pragma unroll
      for (int ni = 0; ni < 4; ++ni) acc[mi][ni] = (f32x4){0.f, 0.f, 0.f, 0.f};

    for (int ch = 0; ch < C / CH; ++ch) {
      const int c0 = ch * CH;
      __syncthreads();               // prior chunk's frag readers done
      // ---- stage A: 512 granules x2 (h,l) ----
      #pragma unroll
      for (int i = 0; i < 2; ++i) {
        int G = i * 256 + t;
        int row = G >> 3, g = G & 7;
        int jpos = g ^ (row & 7);
        size_t src = (size_t)(row0 + row) * C + c0 + g * 8;
        *(short8*)&Ah[row * CH + jpos * 8] = *(const short8*)&zh_g[src];
        *(short8*)&Al[row * CH + jpos * 8] = *(const short8*)&zl_g[src];
      }
      // ---- stage B: 1024 granules x2 (h,l) ----
      #pragma unroll
      for (int i = 0; i < 4; ++i) {
        int G = i * 256 + t;
        int row = G >> 3, g = G & 7;
        int jpos = g ^ (row & 7);
        size_t src = (size_t)(kc0 + row) * C + c0 + g * 8;
        *(short8*)&Bh[row * CH + jpos * 8] = *(const short8*)&eh_g[src];
        *(short8*)&Bl[row * CH + jpos * 8] = *(const short8*)&el_g[src];
      }
      __syncthreads();
      // ---- compute: 2 k-steps of 32 ----
      #pragma unroll
      for (int s = 0; s < 2; ++s) {
        const int q = s * 4 + quad;
        short8 afh[2], afl[2];
        #pragma unroll
        for (int mi = 0; mi < 2; ++mi) {
          int rowl = wm * 32 + mi * 16 + lr;
          int jp = q ^ (rowl & 7);
          afh[mi] = *(short8*)&Ah[rowl * CH + jp * 8];
          afl[mi] = *(short8*)&Al[rowl * CH + jp * 8];
        }
        #pragma unroll
        for (int ni = 0; ni < 4; ++ni) {
          int rowb = wn * 64 + ni * 16 + lr;
          int jp = q ^ (rowb & 7);
          short8 bh = *(short8*)&Bh[rowb * CH + jp * 8];
          short8 bl = *(short8*)&Bl[rowb * CH + jp * 8];
          #pragma unroll
          for (int mi = 0; mi < 2; ++mi) {
            acc[mi][ni] = __builtin_amdgcn_mfma_f32_16x16x32_bf16(afh[mi], bh, acc[mi][ni], 0, 0, 0);
            acc[mi][ni] = __builtin_amdgcn_mfma_f32_16x16x32_bf16(afh[mi], bl, acc[mi][ni], 0, 0, 0);
            acc[mi][ni] = __builtin_amdgcn_mfma_f32_16x16x32_bf16(afl[mi], bh, acc[mi][ni], 0, 0, 0);
          }
        }
      }
    }
    // ---- scoring: u = e2 - 2*g ; running top-2 per row-slot ----
    #pragma unroll
    for (int ni = 0; ni < 4; ++ni) {
      int col = wn * 64 + ni * 16 + lr;
      float e2c = e2s[col];
      float kidx = (float)(kc0 + col);
      #pragma unroll
      for (int mi = 0; mi < 2; ++mi)
        #pragma unroll
        for (int r = 0; r < 4; ++r) {
          float sv = fmaf(-2.f, acc[mi][ni][r], e2c);
          int slot = mi * 4 + r;
          if (sv < v1[slot]) { v2[slot] = v1[slot]; v1[slot] = sv; i1f[slot] = kidx; }
          else if (sv < v2[slot]) v2[slot] = sv;
        }
    }
  }
  // ---- butterfly top-2 merge over the 16 col lanes (lr) ----
  #pragma unroll
  for (int off = 1; off < 16; off <<= 1) {
    #pragma unroll
    for (int s = 0; s < 8; ++s) {
      float ov1 = __shfl_xor(v1[s], off);
      float oi1 = __shfl_xor(i1f[s], off);
      float ov2 = __shfl_xor(v2[s], off);
      bool take = (ov1 < v1[s]) || (ov1 == v1[s] && oi1 < i1f[s]);
      float nv2 = fminf(take ? v1[s] : v2[s], take ? ov2 : ov1);
      if (take) { v1[s] = ov1; i1f[s] = oi1; }
      v2[s] = nv2;
    }
  }
  // ---- write per-wave (col-half) results to LDS, then merge halves ----
  __syncthreads();   // all waves done with staging buffers / compute
  if (lr == 0) {
    #pragma unroll
    for (int mi = 0; mi < 2; ++mi)
      #pragma unroll
      for (int r = 0; r < 4; ++r) {
        int slot = mi * 4 + r;
        int row = wm * 32 + mi * 16 + quad * 4 + r;   // 0..63
        mv1[wn * BM + row] = v1[slot];
        mv2[wn * BM + row] = v2[slot];
        mi1[wn * BM + row] = i1f[slot];
      }
  }
  __syncthreads();
  if (t < BM) {
    float a1 = mv1[t], ai = mi1[t], a2 = mv2[t];
    float c1 = mv1[BM + t], ci = mi1[BM + t], c2 = mv2[BM + t];
    bool take = (c1 < a1) || (c1 == a1 && ci < ai);
    float b1 = take ? c1 : a1;
    float bi = take ? ci : ai;
    float b2 = fminf(fminf(a2, c2), take ? a1 : c1);
    out_idx[row0 + t] = bi;
    if (b2 - b1 < T_FLAG) {
      int p = atomicAdd(&flags[0], 1);
      if (p < NN) { flags[1 + p] = row0 + t; pack[p] = ~0ull; }
    }
  }
}

// ---------- fixup: parallel exact recompute of flagged rows ----------
// Old structure: 1 block per flagged row, serial 256-long f64 FMA chain per
// thread, lane-strided (uncoalesced) emb reads -> 98.8 us latency-bound
// (VALUBusy 14%, Occ 23%, 144 GB/s). New structure: each flagged row's K=1024
// search splits into NCHUNK=16 jobs of 64 codes; within a job each wave
// handles one code at a time with all 64 lanes on the 256-elem dot
// (coalesced float4 loads, 4 f64 FMAs/lane, 6-step double shuffle tree).
// Double accumulation is ~2^-53-exact, so any summation order rounds to the
// identical f32 dot; the final d uses the exact same __fadd/__fsub/__fmul_rn
// sequence as before. Cross-chunk merge via packed (orderable-float(d)<<32 |
// idx) atomicMin == lexicographic (min d, then min idx) — the old tie-break.
#define NCHUNK 16
#define KPC (K / NCHUNK)   // 64 codes per chunk, 16 per wave

__global__ __launch_bounds__(256)
void fixup_k(const float* __restrict__ z, const float* __restrict__ emb,
             const float* __restrict__ e2np, const float* __restrict__ z2np,
             const int* __restrict__ flags, u64* __restrict__ pack) {
  __shared__ float zrow[C];
  int cnt = flags[0];
  if (cnt > NN) cnt = NN;
  const int jobs = cnt * NCHUNK;
  const int t = threadIdx.x;
  const int lane = t & 63, w = t >> 6;
  int lastf = -1;
  for (int job = blockIdx.x; job < jobs; job += gridDim.x) {
    const int f = job >> 4;          // NCHUNK = 16
    const int chunk = job & (NCHUNK - 1);
    const int n = flags[1 + f];
    if (f != lastf) {
      __syncthreads();               // prior iter's zrow readers done
      int b = n >> 12, s = n & (SS - 1);
      zrow[t] = z[((size_t)(b * C + t) << 12) + s];
      __syncthreads();
      lastf = f;
    }
    const float z2 = z2np[n];
    const float4 zv = *(const float4*)&zrow[lane * 4];
    float best = 3.4e38f; int besti = 0x7fffffff;
    const int k0 = chunk * KPC + w * (KPC / 4);
    #pragma unroll 4
    for (int kk = k0; kk < k0 + KPC / 4; ++kk) {
      const float4 ev = *(const float4*)&emb[(size_t)kk * C + lane * 4];
      double acc = (double)zv.x * (double)ev.x;
      acc = fma((double)zv.y, (double)ev.y, acc);
      acc = fma((double)zv.z, (double)ev.z, acc);
      acc = fma((double)zv.w, (double)ev.w, acc);
      #pragma unroll
      for (int off = 32; off; off >>= 1) acc += __shfl_down(acc, off);
      if (lane == 0) {
        float g  = (float)acc;
        float t1 = __fadd_rn(z2, e2np[kk]);
        float d  = __fsub_rn(t1, __fmul_rn(2.f, g));
        if (d < best) { best = d; besti = kk; }   // kk ascending -> first min kept
      }
    }
    if (lane == 0) {
      unsigned u = __float_as_uint(best);
      u = (u & 0x80000000u) ? ~u : (u | 0x80000000u);
      u64 pk = ((u64)u << 32) | (unsigned)besti;
      atomicMin(&pack[f], pk);
    }
  }
}

// ---------- scatter fixup winners to out_idx (before gather2) ----------
__global__ __launch_bounds__(256)
void writeback_k(const int* __restrict__ flags, const u64* __restrict__ pack,
                 float* __restrict__ out_idx) {
  int cnt = flags[0];
  if (cnt > NN) cnt = NN;
  int i = blockIdx.x * 256 + threadIdx.x;
  if (i < cnt) {
    int n = flags[1 + i];
    out_idx[n] = (float)(unsigned)(pack[i] & 0xffffffffull);
  }
}

// ---------- gather via LDS-staged emb rows + loss + histogram ----------
#define GROWS 64
__global__ __launch_bounds__(256)
void gather2_k(const float* __restrict__ z, const float* __restrict__ emb,
               float* __restrict__ out, float* __restrict__ ws,
               float* __restrict__ counts) {
  __shared__ float eb[GROWS * 257];
  __shared__ int idxs[GROWS];
  __shared__ float sc[4];
  const int t = threadIdx.x;
  const int n0 = blockIdx.x * GROWS;
  const int b = n0 >> 12;
  const int s0 = n0 & (SS - 1);
  if (t < GROWS) {
    int id = (int)out[OUT_IDX + n0 + t];
    idxs[t] = id;
    atomicAdd(&counts[id], 1.0f);
  }
  __syncthreads();
  #pragma unroll
  for (int i = 0; i < 16; ++i) {
    int q = i * 256 + t;
    int row = q >> 6, c4 = q & 63;
    float4 v = *(const float4*)&emb[(size_t)idxs[row] * C + c4 * 4];
    int base = row * 257 + c4 * 4;
    eb[base + 0] = v.x; eb[base + 1] = v.y;
    eb[base + 2] = v.z; eb[base + 3] = v.w;
  }
  __syncthreads();
  const int sl = t & 63, cg = t >> 6;
  const float* zb = z + (size_t)b * C * SS + s0 + sl;
  float* ob = out + (size_t)b * C * SS + s0 + sl;
  float l = 0.f;
  #pragma unroll 4
  for (int i = 0; i < 64; ++i) {
    int c = cg * 64 + i;
    float q = eb[sl * 257 + c];
    float zv = zb[(size_t)c * SS];
    float d = q - zv;
    l += d * d;
    ob[(size_t)c * SS] = q;
  }
  #pragma unroll
  for (int off = 32; off; off >>= 1) l += __shfl_down(l, off);
  int lane = t & 63, w = t >> 6;
  if (lane == 0) sc[w] = l;
  __syncthreads();
  if (t == 0)
    atomicAdd(&ws[WS_LOSS], sc[0] + sc[1] + sc[2] + sc[3]);
}

// ---------- finalize scalars ----------
__global__ void finalize_k(const float* __restrict__ ws, float* __restrict__ out) {
  __shared__ float sc[8];
  int t = threadIdx.x;
  float ent = 0.f;
  #pragma unroll
  for (int k = t; k < K; k += 256) {
    float em = ws[WS_CNT + k] * (1.0f / NN);
    ent += em * logf(em + 1e-10f);
  }
  float zd = ws[WS_ZSUM + t] * ws[WS_ESUM + t];
  #pragma unroll
  for (int off = 32; off; off >>= 1) {
    ent += __shfl_down(ent, off);
    zd  += __shfl_down(zd, off);
  }
  int lane = t & 63, w = t >> 6;
  if (lane == 0) { sc[w] = ent; sc[4 + w] = zd; }
  __syncthreads();
  if (t == 0) {
    ent = sc[0] + sc[1] + sc[2] + sc[3];
    zd  = sc[4] + sc[5] + sc[6] + sc[7];
    out[OUT_LOSS] = 1.25f * ws[WS_LOSS] * (1.0f / ZQ_ELEMS);
    out[OUT_PERP] = expf(-ent);
    out[OUT_MD]   = ws[WS_SZ2] * (1.0f / NN) + ws[WS_SE2] * (1.0f / K)
                  - 2.0f * zd * (1.0f / ((float)NN * (float)K));
  }
}

extern "C" void kernel_launch(void* const* d_in, const int* in_sizes, int n_in,
                              void* d_out, int out_size, void* d_ws, size_t ws_size,
                              hipStream_t stream) {
  const float* z   = (const float*)d_in[0];
  const float* emb = (const float*)d_in[1];
  float* out = (float*)d_out;
  float* ws  = (float*)d_ws;
  int* flags = (int*)(ws + WS_FLG);
  u64* pack  = (u64*)(ws + WS_PACK);
  u16* eh_g = (u16*)(ws + WS_EH);
  u16* el_g = (u16*)(ws + WS_EL);
  // zh/zl live in d_out's zq region; overwritten by gather2_k at the end.
  u16* zh_g = (u16*)d_out;
  u16* zl_g = zh_g + (size_t)ZQ_ELEMS;
  (void)in_sizes; (void)n_in; (void)out_size; (void)ws_size;

  hipMemsetAsync(d_ws, 0, WS_E2R * sizeof(float), stream);
  hipMemsetAsync(ws + WS_FLG, 0, sizeof(int), stream);
  emb_prep_k<<<64, 256, 0, stream>>>(emb, ws, eh_g, el_g);
  prep_z_k<<<NN / MROWS, 256, 0, stream>>>(z, ws, zh_g, zl_g);
  size_t lds = (size_t)(2 * BM * CH + 2 * BN * CH) * sizeof(u16)
             + (BN + 6 * BM) * sizeof(float);
  vq_mfma_k<<<NN / BM, 256, lds, stream>>>(zh_g, zl_g, eh_g, el_g,
                                           ws + WS_E2R, out + OUT_IDX, flags, pack);
  fixup_k<<<4096, 256, 0, stream>>>(z, emb, ws + WS_E2R, ws + WS_Z2N, flags, pack);
  writeback_k<<<NN / 256, 256, 0, stream>>>(flags, pack, out + OUT_IDX);
  gather2_k<<<NN / GROWS, 256, 0, stream>>>(z, emb, out, ws, ws + WS_CNT);
  finalize_k<<<1, 256, 0, stream>>>(ws, out);
}

// Round 2
// 228.375 us; speedup vs baseline: 1.3674x; 1.3674x over previous
//
#include <hip/hip_runtime.h>
#include <math.h>

// Problem constants
#define C 256
#define K 1024
#define SS 4096          // 16*16*16 spatial
#define NB 8             // batch
#define NN 32768         // NB*SS rows
#define ZQ_ELEMS 8388608 // NB*C*SS
#define OUT_LOSS 8388608
#define OUT_PERP 8388609
#define OUT_IDX  8388610
#define OUT_MD   8421378

// workspace float layout
#define WS_SZ2   0       // sum z^2 (scalar)
#define WS_SE2   1       // sum e^2 (scalar)
#define WS_LOSS  2       // sum (zq-z)^2 (scalar)
#define WS_ZSUM  8       // [256] column sums of zf
#define WS_ESUM  264     // [256] column sums of emb
#define WS_CNT   520     // [1024] histogram (float)
#define WS_E2R   1544    // [1024] ||e_k||^2, numpy-pairwise f32
#define WS_Z2N   2568    // [32768] ||z_n||^2, numpy-pairwise f32
#define WS_FLG   35336   // int region: [0]=qcount, [1..NN]= n | (c<<16)
#define WS_EH    68608   // [1024*256] u16 emb-hi
#define WS_EL    199680  // [1024*256] u16 emb-lo
#define WS_CAND  330752  // [NN*4] u16 candidate code indices per queue slot

// Candidate machinery: the reference computes d = fl(fl(z2+e2) - fl(2g)),
// quantized at ulp(d~256)=3.05e-5. We replicate that rounding in-kernel, so
// the argmin is certain unless a competitor sits within ~2ulp of the winner
// (a +-1ulp flip from our |g_mfma - g_ref| <~ 1e-6). Windows (relative,
// auto-ulp-scaling): collect at M*9.6e-7 (8-16 ulp), keep at d1*6.0e-7
// (5-10 ulp) -- covers g-error up to ~ulp/2 ~ 2.3e-5, 20x worst-case model.
#define TC_FACT 9.6e-7f
#define TF_FACT 6.0e-7f
#define CAP 4            // max candidates per flagged row in global queue
#define CAP_BIG 16       // LDS collection capacity per row
#define OV 7             // sentinel count: full-scan fallback

typedef __attribute__((ext_vector_type(8))) short short8;
typedef __attribute__((ext_vector_type(4))) float f32x4;
typedef unsigned short u16;

__device__ inline u16 f2bf(float x) {  // f32 -> bf16 RNE
  unsigned u = __float_as_uint(x);
  unsigned r = (u + 0x7fffu + ((u >> 16) & 1u)) >> 16;
  return (u16)r;
}
__device__ inline float bf2f(u16 h) { return __uint_as_float(((unsigned)h) << 16); }

// ---- numpy pairwise f32 sum of squares, 256 contiguous elements ----
__device__ inline float np_sumsq_256(const float* __restrict__ a) {
  float tot = 0.f;
  #pragma unroll
  for (int h = 0; h < 2; ++h) {
    const float* p = a + 128 * h;
    float r[8];
    #pragma unroll
    for (int j = 0; j < 8; ++j) r[j] = __fmul_rn(p[j], p[j]);
    for (int i = 8; i < 128; i += 8) {
      #pragma unroll
      for (int j = 0; j < 8; ++j) {
        float v = p[i + j];
        r[j] = __fadd_rn(r[j], __fmul_rn(v, v));
      }
    }
    float s01 = __fadd_rn(r[0], r[1]);
    float s23 = __fadd_rn(r[2], r[3]);
    float s45 = __fadd_rn(r[4], r[5]);
    float s67 = __fadd_rn(r[6], r[7]);
    float res = __fadd_rn(__fadd_rn(s01, s23), __fadd_rn(s45, s67));
    tot = (h == 0) ? res : __fadd_rn(tot, res);
  }
  return tot;
}

// ---------- emb prep: split to eh/el, e2[k], col sums, Se2 ----------
__global__ __launch_bounds__(256)
void emb_prep_k(const float* __restrict__ emb, float* __restrict__ ws,
                u16* __restrict__ eh, u16* __restrict__ el) {
  int r0 = blockIdx.x * 16;   // 64 blocks x 16 rows
  int t = threadIdx.x;
  float s = 0.f;
  #pragma unroll
  for (int i = 0; i < 16; ++i) {
    size_t idx = (size_t)(r0 + i) * C + t;
    float v = emb[idx];
    s += v;
    u16 h = f2bf(v);
    eh[idx] = h;
    el[idx] = f2bf(v - bf2f(h));
  }
  atomicAdd(&ws[WS_ESUM + t], s);
  if (t < 16) {
    float e2 = np_sumsq_256(emb + (size_t)(r0 + t) * C);
    ws[WS_E2R + r0 + t] = e2;
    atomicAdd(&ws[WS_SE2], e2);
  }
}

#define MROWS 64
#define ZS_STRIDE 260

// ---------- one pass over z: zsum[c], Sz2, z2np[n], bf16 split zh/zl ----------
__global__ __launch_bounds__(256)
void prep_z_k(const float* __restrict__ z, float* __restrict__ ws,
              u16* __restrict__ zh_g, u16* __restrict__ zl_g) {
  __shared__ float zs[MROWS * ZS_STRIDE];
  const int t = threadIdx.x;
  const int n0 = blockIdx.x * MROWS;
  const int b = n0 / SS;
  const int s0 = n0 % SS;
  {
    const int sl = t & 63, cg = t >> 6;
    const float* zb = z + (size_t)b * C * SS + s0 + sl;
    #pragma unroll
    for (int i = 0; i < 16; ++i) {
      int c = (cg * 16 + i) * 4;
      float4 v;
      v.x = zb[(size_t)(c + 0) * SS];
      v.y = zb[(size_t)(c + 1) * SS];
      v.z = zb[(size_t)(c + 2) * SS];
      v.w = zb[(size_t)(c + 3) * SS];
      *(float4*)&zs[sl * ZS_STRIDE + c] = v;
    }
  }
  __syncthreads();
  // column sums
  {
    float s = 0.f;
    #pragma unroll 8
    for (int r = 0; r < MROWS; ++r) s += zs[r * ZS_STRIDE + t];
    atomicAdd(&ws[WS_ZSUM + t], s);
  }
  // bf16 split, lane-linear coalesced short8 stores
  {
    #pragma unroll
    for (int i = 0; i < 8; ++i) {
      int q = i * 256 + t;          // short8 chunk 0..2047
      int row = q >> 5;             // 0..63
      int c0 = (q & 31) * 8;
      float4 va = *(const float4*)&zs[row * ZS_STRIDE + c0];
      float4 vb = *(const float4*)&zs[row * ZS_STRIDE + c0 + 4];
      float f[8] = {va.x, va.y, va.z, va.w, vb.x, vb.y, vb.z, vb.w};
      short8 hv, lv;
      #pragma unroll
      for (int j = 0; j < 8; ++j) {
        u16 h = f2bf(f[j]);
        hv[j] = (short)h;
        lv[j] = (short)f2bf(f[j] - bf2f(h));
      }
      size_t off = (size_t)(n0 + row) * C + c0;
      *(short8*)&zh_g[off] = hv;
      *(short8*)&zl_g[off] = lv;
    }
  }
  // z2 (numpy-pairwise) + Sz2
  if (t < MROWS) {
    float z2 = np_sumsq_256(&zs[t * ZS_STRIDE]);
    ws[WS_Z2N + n0 + t] = z2;
    #pragma unroll
    for (int off = 32; off; off >>= 1) z2 += __shfl_down(z2, off);
    if (t == 0) atomicAdd(&ws[WS_SZ2], z2);
  }
}

// ---------- main: split-bf16 MFMA + reference-rounded dq + candidate lists ----------
// BM=64 -> grid 512 -> 2 blocks/CU co-resident. Waves 2x2: wave(wm,wn) =
// rows wm*32..+31 (mi 0..1) x cols wn*64..+63 (ni 0..3). Col halves merged
// at the end via LDS. ~56 KB LDS.
#define BM 64
#define BN 128
#define CH 64

__global__ __launch_bounds__(256, 2)
void vq_mfma_k(const u16* __restrict__ zh_g, const u16* __restrict__ zl_g,
               const u16* __restrict__ eh_g, const u16* __restrict__ el_g,
               const float* __restrict__ e2row, const float* __restrict__ z2np,
               float* __restrict__ out_idx,
               int* __restrict__ qarr, u16* __restrict__ cand) {
  extern __shared__ u16 smem_u16[];
  u16* Ah = smem_u16;                 // [64][64] u16, swizzled
  u16* Al = Ah + BM * CH;
  u16* Bh = Al + BM * CH;             // [128][64]
  u16* Bl = Bh + BN * CH;
  float* e2s = (float*)(Bl + BN * CH);   // [128]
  float* mv1 = e2s + BN;              // [2][64] col-half merge (values)
  float* mi1 = mv1 + 2 * BM;          // [2][64] col-half merge (indices)
  float* z2s = mi1 + 2 * BM;          // [64] per-row z2
  float* lval = z2s + BM;             // [64][CAP_BIG] candidate dq values
  unsigned* Mlds = (unsigned*)(lval + BM * CAP_BIG);  // [64] running row min
  unsigned* cntl = Mlds + BM;         // [64] append counters
  u16* lidx = (u16*)(cntl + BM);      // [64][CAP_BIG] candidate code idx

  const int t = threadIdx.x;
  const int lane = t & 63;
  const int wid = t >> 6;
  const int wm = wid >> 1, wn = wid & 1;
  const int quad = lane >> 4, lr = lane & 15;
  const int row0 = blockIdx.x * BM;

  if (t < BM) {
    z2s[t] = z2np[row0 + t];
    Mlds[t] = 0x7F800000u;  // +inf (positive floats order as uints)
    cntl[t] = 0u;
  }

  // running top-1 per slot (mi*4 + r), cols restricted to this wave's half
  float v1[8], i1f[8];
  #pragma unroll
  for (int s = 0; s < 8; ++s) { v1[s] = 3.4e38f; i1f[s] = 0.f; }

  for (int nt = 0; nt < K / BN; ++nt) {
    const int kc0 = nt * BN;
    __syncthreads();                 // prior n-tile's e2s/list-phase readers done
    if (t < BN) e2s[t] = e2row[kc0 + t];

    f32x4 acc[2][4];
    #pragma unroll
    for (int mi = 0; mi < 2; ++mi)
      #pragma unroll
      for (int ni = 0; ni < 4; ++ni) acc[mi][ni] = (f32x4){0.f, 0.f, 0.f, 0.f};

    for (int ch = 0; ch < C / CH; ++ch) {
      const int c0 = ch * CH;
      __syncthreads();               // prior chunk's frag readers done
      // ---- stage A: 512 granules x2 (h,l) ----
      #pragma unroll
      for (int i = 0; i < 2; ++i) {
        int G = i * 256 + t;
        int row = G >> 3, g = G & 7;
        int jpos = g ^ (row & 7);
        size_t src = (size_t)(row0 + row) * C + c0 + g * 8;
        *(short8*)&Ah[row * CH + jpos * 8] = *(const short8*)&zh_g[src];
        *(short8*)&Al[row * CH + jpos * 8] = *(const short8*)&zl_g[src];
      }
      // ---- stage B: 1024 granules x2 (h,l) ----
      #pragma unroll
      for (int i = 0; i < 4; ++i) {
        int G = i * 256 + t;
        int row = G >> 3, g = G & 7;
        int jpos = g ^ (row & 7);
        size_t src = (size_t)(kc0 + row) * C + c0 + g * 8;
        *(short8*)&Bh[row * CH + jpos * 8] = *(const short8*)&eh_g[src];
        *(short8*)&Bl[row * CH + jpos * 8] = *(const short8*)&el_g[src];
      }
      __syncthreads();
      // ---- compute: 2 k-steps of 32 ----
      #pragma unroll
      for (int s = 0; s < 2; ++s) {
        const int q = s * 4 + quad;
        short8 afh[2], afl[2];
        #pragma unroll
        for (int mi = 0; mi < 2; ++mi) {
          int rowl = wm * 32 + mi * 16 + lr;
          int jp = q ^ (rowl & 7);
          afh[mi] = *(short8*)&Ah[rowl * CH + jp * 8];
          afl[mi] = *(short8*)&Al[rowl * CH + jp * 8];
        }
        #pragma unroll
        for (int ni = 0; ni < 4; ++ni) {
          int rowb = wn * 64 + ni * 16 + lr;
          int jp = q ^ (rowb & 7);
          short8 bh = *(short8*)&Bh[rowb * CH + jp * 8];
          short8 bl = *(short8*)&Bl[rowb * CH + jp * 8];
          #pragma unroll
          for (int mi = 0; mi < 2; ++mi) {
            acc[mi][ni] = __builtin_amdgcn_mfma_f32_16x16x32_bf16(afh[mi], bh, acc[mi][ni], 0, 0, 0);
            acc[mi][ni] = __builtin_amdgcn_mfma_f32_16x16x32_bf16(afh[mi], bl, acc[mi][ni], 0, 0, 0);
            acc[mi][ni] = __builtin_amdgcn_mfma_f32_16x16x32_bf16(afl[mi], bh, acc[mi][ni], 0, 0, 0);
          }
        }
      }
    }
    // ---- scoring phase 1: fold this tile's dq into per-row running min ----
    // dq replicates the reference's rounding: fl(fl(z2+e2) - fl(2g)).
    #pragma unroll
    for (int mi = 0; mi < 2; ++mi)
      #pragma unroll
      for (int r = 0; r < 4; ++r) {
        int row = wm * 32 + mi * 16 + quad * 4 + r;
        float z2r = z2s[row];
        float m4 = 3.4e38f;
        #pragma unroll
        for (int ni = 0; ni < 4; ++ni) {
          int col = wn * 64 + ni * 16 + lr;
          float dq = __fsub_rn(__fadd_rn(z2r, e2s[col]),
                               __fmul_rn(2.f, acc[mi][ni][r]));
          m4 = fminf(m4, dq);
        }
        atomicMin(&Mlds[row], __float_as_uint(m4));
      }
    __syncthreads();
    // ---- scoring phase 2: top-1 track + candidate collect ----
    #pragma unroll
    for (int mi = 0; mi < 2; ++mi)
      #pragma unroll
      for (int r = 0; r < 4; ++r) {
        int row = wm * 32 + mi * 16 + quad * 4 + r;
        float z2r = z2s[row];
        float M = __uint_as_float(Mlds[row]);
        float thr = fmaf(M, TC_FACT, M);
        int slot = mi * 4 + r;
        #pragma unroll
        for (int ni = 0; ni < 4; ++ni) {
          int col = wn * 64 + ni * 16 + lr;
          float dq = __fsub_rn(__fadd_rn(z2r, e2s[col]),
                               __fmul_rn(2.f, acc[mi][ni][r]));
          // strict < keeps first (smallest col) on ties; cols ascend in nt,ni
          if (dq < v1[slot]) { v1[slot] = dq; i1f[slot] = (float)(kc0 + col); }
          if (dq < thr) {
            unsigned p = atomicAdd(&cntl[row], 1u);
            if (p < CAP_BIG) {
              lval[row * CAP_BIG + p] = dq;
              lidx[row * CAP_BIG + p] = (u16)(kc0 + col);
            }
          }
        }
      }
  }
  // ---- butterfly top-1 merge over the 16 col lanes (lr) ----
  #pragma unroll
  for (int off = 1; off < 16; off <<= 1) {
    #pragma unroll
    for (int s = 0; s < 8; ++s) {
      float ov1 = __shfl_xor(v1[s], off);
      float oi1 = __shfl_xor(i1f[s], off);
      bool take = (ov1 < v1[s]) || (ov1 == v1[s] && oi1 < i1f[s]);
      if (take) { v1[s] = ov1; i1f[s] = oi1; }
    }
  }
  // ---- write per-wave (col-half) results to LDS, then merge halves ----
  __syncthreads();   // all waves done with staging buffers / compute / appends
  if (lr == 0) {
    #pragma unroll
    for (int mi = 0; mi < 2; ++mi)
      #pragma unroll
      for (int r = 0; r < 4; ++r) {
        int slot = mi * 4 + r;
        int row = wm * 32 + mi * 16 + quad * 4 + r;   // 0..63
        mv1[wn * BM + row] = v1[slot];
        mi1[wn * BM + row] = i1f[slot];
      }
  }
  __syncthreads();
  if (t < BM) {
    float a1 = mv1[t], ai = mi1[t];
    float c1 = mv1[BM + t], ci = mi1[BM + t];
    bool take = (c1 < a1) || (c1 == a1 && ci < ai);
    float b1 = take ? c1 : a1;
    float bi = take ? ci : ai;
    out_idx[row0 + t] = bi;    // provisional winner (fixup overwrites flagged)
    // filter collected candidates against the final row min
    unsigned raw = cntl[t];
    float tf = fmaf(b1, TF_FACT, b1);
    int c = 0;
    u16 keep[CAP];
    bool ov = raw > (unsigned)CAP_BIG;
    if (!ov) {
      for (unsigned j = 0; j < raw; ++j) {
        if (lval[t * CAP_BIG + j] <= tf) {
          if (c < CAP) keep[c] = lidx[t * CAP_BIG + j];
          ++c;
        }
      }
      if (c > CAP) ov = true;
    }
    if (ov || c > 1) {
      int q = atomicAdd(&qarr[0], 1);
      int cc = ov ? OV : c;
      qarr[1 + q] = (row0 + t) | (cc << 16);
      if (!ov)
        #pragma unroll
        for (int j = 0; j < CAP; ++j)
          cand[(size_t)q * CAP + j] = (j < c) ? keep[j] : (u16)0;
    }
  }
}

// ---------- fixup: exact f64-rounded f32 dots for queued candidates ----------
// One wave per queue entry; <=CAP candidates, each a 64-lane coalesced
// float4 dot + 6-step f64 butterfly, then the reference's rounding sequence
// and lexicographic (d, idx) min == first-index argmin tie-break.
__global__ __launch_bounds__(256)
void fixup_k(const float* __restrict__ z, const float* __restrict__ emb,
             const float* __restrict__ e2np, const float* __restrict__ z2np,
             const int* __restrict__ qarr, const u16* __restrict__ cand,
             float* __restrict__ out_idx) {
  int qcnt = qarr[0];
  if (qcnt > NN) qcnt = NN;
  const int t = threadIdx.x;
  const int lane = t & 63, w = t >> 6;
  for (int q = blockIdx.x * 4 + w; q < qcnt; q += gridDim.x * 4) {
    int e = qarr[1 + q];
    int n = e & 0xffff;
    int c = e >> 16;
    int b = n >> 12, s = n & (SS - 1);
    float z2 = z2np[n];
    // lane's 4 z components (stride-SS gather; L2/L3-hot after prep_z)
    const float* zb = z + (((size_t)b * C) << 12) + s;
    float4 zv;
    zv.x = zb[((size_t)(lane * 4 + 0)) << 12];
    zv.y = zb[((size_t)(lane * 4 + 1)) << 12];
    zv.z = zb[((size_t)(lane * 4 + 2)) << 12];
    zv.w = zb[((size_t)(lane * 4 + 3)) << 12];
    float bestd = 3.4e38f;
    int besti = 0x7fffffff;
    const int nc = (c == OV) ? K : c;
    for (int j = 0; j < nc; ++j) {
      int kk = (c == OV) ? j : (int)cand[(size_t)q * CAP + j];
      const float4 ev = *(const float4*)&emb[(size_t)kk * C + lane * 4];
      double acc = (double)zv.x * (double)ev.x;
      acc = fma((double)zv.y, (double)ev.y, acc);
      acc = fma((double)zv.z, (double)ev.z, acc);
      acc = fma((double)zv.w, (double)ev.w, acc);
      #pragma unroll
      for (int off = 32; off; off >>= 1) acc += __shfl_xor(acc, off);
      float g  = (float)acc;           // correctly-rounded f32 dot
      float t1 = __fadd_rn(z2, e2np[kk]);
      float d  = __fsub_rn(t1, __fmul_rn(2.f, g));
      if (d < bestd || (d == bestd && kk < besti)) { bestd = d; besti = kk; }
    }
    if (lane == 0) out_idx[n] = (float)besti;
  }
}

// ---------- gather via LDS-staged emb rows + loss + histogram ----------
#define GROWS 64
__global__ __launch_bounds__(256)
void gather2_k(const float* __restrict__ z, const float* __restrict__ emb,
               float* __restrict__ out, float* __restrict__ ws,
               float* __restrict__ counts) {
  __shared__ float eb[GROWS * 257];
  __shared__ int idxs[GROWS];
  __shared__ float sc[4];
  const int t = threadIdx.x;
  const int n0 = blockIdx.x * GROWS;
  const int b = n0 >> 12;
  const int s0 = n0 & (SS - 1);
  if (t < GROWS) {
    int id = (int)out[OUT_IDX + n0 + t];
    idxs[t] = id;
    atomicAdd(&counts[id], 1.0f);
  }
  __syncthreads();
  #pragma unroll
  for (int i = 0; i < 16; ++i) {
    int q = i * 256 + t;
    int row = q >> 6, c4 = q & 63;
    float4 v = *(const float4*)&emb[(size_t)idxs[row] * C + c4 * 4];
    int base = row * 257 + c4 * 4;
    eb[base + 0] = v.x; eb[base + 1] = v.y;
    eb[base + 2] = v.z; eb[base + 3] = v.w;
  }
  __syncthreads();
  const int sl = t & 63, cg = t >> 6;
  const float* zb = z + (size_t)b * C * SS + s0 + sl;
  float* ob = out + (size_t)b * C * SS + s0 + sl;
  float l = 0.f;
  #pragma unroll 4
  for (int i = 0; i < 64; ++i) {
    int c = cg * 64 + i;
    float q = eb[sl * 257 + c];
    float zv = zb[(size_t)c * SS];
    float d = q - zv;
    l += d * d;
    ob[(size_t)c * SS] = q;
  }
  #pragma unroll
  for (int off = 32; off; off >>= 1) l += __shfl_down(l, off);
  int lane = t & 63, w = t >> 6;
  if (lane == 0) sc[w] = l;
  __syncthreads();
  if (t == 0)
    atomicAdd(&ws[WS_LOSS], sc[0] + sc[1] + sc[2] + sc[3]);
}

// ---------- finalize scalars ----------
__global__ void finalize_k(const float* __restrict__ ws, float* __restrict__ out) {
  __shared__ float sc[8];
  int t = threadIdx.x;
  float ent = 0.f;
  #pragma unroll
  for (int k = t; k < K; k += 256) {
    float em = ws[WS_CNT + k] * (1.0f / NN);
    ent += em * logf(em + 1e-10f);
  }
  float zd = ws[WS_ZSUM + t] * ws[WS_ESUM + t];
  #pragma unroll
  for (int off = 32; off; off >>= 1) {
    ent += __shfl_down(ent, off);
    zd  += __shfl_down(zd, off);
  }
  int lane = t & 63, w = t >> 6;
  if (lane == 0) { sc[w] = ent; sc[4 + w] = zd; }
  __syncthreads();
  if (t == 0) {
    ent = sc[0] + sc[1] + sc[2] + sc[3];
    zd  = sc[4] + sc[5] + sc[6] + sc[7];
    out[OUT_LOSS] = 1.25f * ws[WS_LOSS] * (1.0f / ZQ_ELEMS);
    out[OUT_PERP] = expf(-ent);
    out[OUT_MD]   = ws[WS_SZ2] * (1.0f / NN) + ws[WS_SE2] * (1.0f / K)
                  - 2.0f * zd * (1.0f / ((float)NN * (float)K));
  }
}

extern "C" void kernel_launch(void* const* d_in, const int* in_sizes, int n_in,
                              void* d_out, int out_size, void* d_ws, size_t ws_size,
                              hipStream_t stream) {
  const float* z   = (const float*)d_in[0];
  const float* emb = (const float*)d_in[1];
  float* out = (float*)d_out;
  float* ws  = (float*)d_ws;
  int* qarr = (int*)(ws + WS_FLG);
  u16* cand = (u16*)(ws + WS_CAND);
  u16* eh_g = (u16*)(ws + WS_EH);
  u16* el_g = (u16*)(ws + WS_EL);
  // zh/zl live in d_out's zq region; overwritten by gather2_k at the end.
  u16* zh_g = (u16*)d_out;
  u16* zl_g = zh_g + (size_t)ZQ_ELEMS;
  (void)in_sizes; (void)n_in; (void)out_size; (void)ws_size;

  hipMemsetAsync(d_ws, 0, WS_E2R * sizeof(float), stream);
  hipMemsetAsync(ws + WS_FLG, 0, sizeof(int), stream);
  emb_prep_k<<<64, 256, 0, stream>>>(emb, ws, eh_g, el_g);
  prep_z_k<<<NN / MROWS, 256, 0, stream>>>(z, ws, zh_g, zl_g);
  size_t lds = (size_t)(2 * BM * CH + 2 * BN * CH) * sizeof(u16)
             + (size_t)(BN + 4 * BM + BM + BM * CAP_BIG) * sizeof(float)
             + (size_t)(2 * BM) * sizeof(unsigned)
             + (size_t)(BM * CAP_BIG) * sizeof(u16);
  vq_mfma_k<<<NN / BM, 256, lds, stream>>>(zh_g, zl_g, eh_g, el_g,
                                           ws + WS_E2R, ws + WS_Z2N,
                                           out + OUT_IDX, qarr, cand);
  fixup_k<<<2048, 256, 0, stream>>>(z, emb, ws + WS_E2R, ws + WS_Z2N,
                                    qarr, cand, out + OUT_IDX);
  gather2_k<<<NN / GROWS, 256, 0, stream>>>(z, emb, out, ws, ws + WS_CNT);
  finalize_k<<<1, 256, 0, stream>>>(ws, out);
}

// Round 3
// 225.210 us; speedup vs baseline: 1.3866x; 1.0141x over previous
//
#include <hip/hip_runtime.h>
#include <math.h>

// Problem constants
#define C 256
#define K 1024
#define SS 4096          // 16*16*16 spatial
#define NB 8             // batch
#define NN 32768         // NB*SS rows
#define ZQ_ELEMS 8388608 // NB*C*SS
#define OUT_LOSS 8388608
#define OUT_PERP 8388609
#define OUT_IDX  8388610
#define OUT_MD   8421378

// workspace float layout
#define WS_SZ2   0       // sum z^2 (scalar)
#define WS_SE2   1       // sum e^2 (scalar)
#define WS_LOSS  2       // sum (zq-z)^2 (scalar)
#define WS_ZSUM  8       // [256] column sums of zf
#define WS_ESUM  264     // [256] column sums of emb
#define WS_CNT   520     // [1024] histogram (float)
#define WS_E2R   1544    // [1024] ||e_k||^2, numpy-pairwise f32
#define WS_Z2N   2568    // [32768] ||z_n||^2, numpy-pairwise f32
#define WS_FLG   35336   // int region: [0]=qcount, [1..NN]= n | (c<<16)
#define WS_EH    68608   // [1024*256] u16 emb-hi
#define WS_EL    199680  // [1024*256] u16 emb-lo
#define WS_CAND  330752  // [NN*4] u16 candidate code indices per queue slot

// Candidate machinery: the reference computes d = fl(fl(z2+e2) - fl(2g)),
// quantized at ulp(d~256)=3.05e-5. We replicate that rounding in-kernel, so
// the argmin is certain unless a competitor sits within ~2ulp of the winner
// (a +-1ulp flip from our |g_mfma - g_ref| <~ 1e-6). Windows (relative,
// auto-ulp-scaling): collect at M*9.6e-7 (8-16 ulp), keep at d1*6.0e-7
// (5-10 ulp) -- covers g-error up to ~ulp/2 ~ 2.3e-5, 20x worst-case model.
#define TC_FACT 9.6e-7f
#define TF_FACT 6.0e-7f
#define CAP 4            // max candidates per flagged row in global queue
#define CAP_BIG 16       // LDS collection capacity per row
#define OV 7             // sentinel count: full-scan fallback

typedef __attribute__((ext_vector_type(8))) short short8;
typedef __attribute__((ext_vector_type(4))) float f32x4;
typedef unsigned short u16;

__device__ inline u16 f2bf(float x) {  // f32 -> bf16 RNE
  unsigned u = __float_as_uint(x);
  unsigned r = (u + 0x7fffu + ((u >> 16) & 1u)) >> 16;
  return (u16)r;
}
__device__ inline float bf2f(u16 h) { return __uint_as_float(((unsigned)h) << 16); }

// async global->LDS 16B: LDS dest is wave-uniform base + lane*16 (linear);
// swizzle is applied on the per-lane GLOBAL address instead (m173 pattern).
__device__ __forceinline__ void gl_lds16(const u16* g, u16* l) {
  __builtin_amdgcn_global_load_lds(
      (const __attribute__((address_space(1))) unsigned int*)g,
      (__attribute__((address_space(3))) unsigned int*)l,
      16, 0, 0);
}

// ---- numpy pairwise f32 sum of squares, 256 contiguous elements ----
__device__ inline float np_sumsq_256(const float* __restrict__ a) {
  float tot = 0.f;
  #pragma unroll
  for (int h = 0; h < 2; ++h) {
    const float* p = a + 128 * h;
    float r[8];
    #pragma unroll
    for (int j = 0; j < 8; ++j) r[j] = __fmul_rn(p[j], p[j]);
    for (int i = 8; i < 128; i += 8) {
      #pragma unroll
      for (int j = 0; j < 8; ++j) {
        float v = p[i + j];
        r[j] = __fadd_rn(r[j], __fmul_rn(v, v));
      }
    }
    float s01 = __fadd_rn(r[0], r[1]);
    float s23 = __fadd_rn(r[2], r[3]);
    float s45 = __fadd_rn(r[4], r[5]);
    float s67 = __fadd_rn(r[6], r[7]);
    float res = __fadd_rn(__fadd_rn(s01, s23), __fadd_rn(s45, s67));
    tot = (h == 0) ? res : __fadd_rn(tot, res);
  }
  return tot;
}

// ---------- emb prep: split to eh/el, e2[k], col sums, Se2 ----------
__global__ __launch_bounds__(256)
void emb_prep_k(const float* __restrict__ emb, float* __restrict__ ws,
                u16* __restrict__ eh, u16* __restrict__ el) {
  int r0 = blockIdx.x * 16;   // 64 blocks x 16 rows
  int t = threadIdx.x;
  float s = 0.f;
  #pragma unroll
  for (int i = 0; i < 16; ++i) {
    size_t idx = (size_t)(r0 + i) * C + t;
    float v = emb[idx];
    s += v;
    u16 h = f2bf(v);
    eh[idx] = h;
    el[idx] = f2bf(v - bf2f(h));
  }
  atomicAdd(&ws[WS_ESUM + t], s);
  if (t < 16) {
    float e2 = np_sumsq_256(emb + (size_t)(r0 + t) * C);
    ws[WS_E2R + r0 + t] = e2;
    atomicAdd(&ws[WS_SE2], e2);
  }
}

#define MROWS 64
#define ZS_STRIDE 260

// ---------- one pass over z: zsum[c], Sz2, z2np[n], bf16 split zh/zl ----------
__global__ __launch_bounds__(256)
void prep_z_k(const float* __restrict__ z, float* __restrict__ ws,
              u16* __restrict__ zh_g, u16* __restrict__ zl_g) {
  __shared__ float zs[MROWS * ZS_STRIDE];
  const int t = threadIdx.x;
  const int n0 = blockIdx.x * MROWS;
  const int b = n0 / SS;
  const int s0 = n0 % SS;
  {
    const int sl = t & 63, cg = t >> 6;
    const float* zb = z + (size_t)b * C * SS + s0 + sl;
    #pragma unroll
    for (int i = 0; i < 16; ++i) {
      int c = (cg * 16 + i) * 4;
      float4 v;
      v.x = zb[(size_t)(c + 0) * SS];
      v.y = zb[(size_t)(c + 1) * SS];
      v.z = zb[(size_t)(c + 2) * SS];
      v.w = zb[(size_t)(c + 3) * SS];
      *(float4*)&zs[sl * ZS_STRIDE + c] = v;
    }
  }
  __syncthreads();
  // column sums
  {
    float s = 0.f;
    #pragma unroll 8
    for (int r = 0; r < MROWS; ++r) s += zs[r * ZS_STRIDE + t];
    atomicAdd(&ws[WS_ZSUM + t], s);
  }
  // bf16 split, lane-linear coalesced short8 stores
  {
    #pragma unroll
    for (int i = 0; i < 8; ++i) {
      int q = i * 256 + t;          // short8 chunk 0..2047
      int row = q >> 5;             // 0..63
      int c0 = (q & 31) * 8;
      float4 va = *(const float4*)&zs[row * ZS_STRIDE + c0];
      float4 vb = *(const float4*)&zs[row * ZS_STRIDE + c0 + 4];
      float f[8] = {va.x, va.y, va.z, va.w, vb.x, vb.y, vb.z, vb.w};
      short8 hv, lv;
      #pragma unroll
      for (int j = 0; j < 8; ++j) {
        u16 h = f2bf(f[j]);
        hv[j] = (short)h;
        lv[j] = (short)f2bf(f[j] - bf2f(h));
      }
      size_t off = (size_t)(n0 + row) * C + c0;
      *(short8*)&zh_g[off] = hv;
      *(short8*)&zl_g[off] = lv;
    }
  }
  // z2 (numpy-pairwise) + Sz2
  if (t < MROWS) {
    float z2 = np_sumsq_256(&zs[t * ZS_STRIDE]);
    ws[WS_Z2N + n0 + t] = z2;
    #pragma unroll
    for (int off = 32; off; off >>= 1) z2 += __shfl_down(z2, off);
    if (t == 0) atomicAdd(&ws[WS_SZ2], z2);
  }
}

// ---------- main: split-bf16 MFMA + reference-rounded dq + candidate lists ----------
// BM=64 -> grid 512 -> 2 blocks/CU co-resident. Waves 2x2: wave(wm,wn) =
// rows wm*32..+31 (mi 0..1) x cols wn*64..+63 (ni 0..3). Col halves merged
// at the end via LDS. ~56 KB LDS.
// Staging is global_load_lds width=16 (R3): LDS dest linear, per-lane global
// address carries the inverse XOR swizzle. Since 8-row groups are aligned,
// source granule = (lane&7) ^ (lane>>3) -- a per-lane constant.
#define BM 64
#define BN 128
#define CH 64

__global__ __launch_bounds__(256, 2)
void vq_mfma_k(const u16* __restrict__ zh_g, const u16* __restrict__ zl_g,
               const u16* __restrict__ eh_g, const u16* __restrict__ el_g,
               const float* __restrict__ e2row, const float* __restrict__ z2np,
               float* __restrict__ out_idx,
               int* __restrict__ qarr, u16* __restrict__ cand) {
  extern __shared__ u16 smem_u16[];
  u16* Ah = smem_u16;                 // [64][64] u16, swizzled
  u16* Al = Ah + BM * CH;
  u16* Bh = Al + BM * CH;             // [128][64]
  u16* Bl = Bh + BN * CH;
  float* e2s = (float*)(Bl + BN * CH);   // [128]
  float* mv1 = e2s + BN;              // [2][64] col-half merge (values)
  float* mi1 = mv1 + 2 * BM;          // [2][64] col-half merge (indices)
  float* z2s = mi1 + 2 * BM;          // [64] per-row z2
  float* lval = z2s + BM;             // [64][CAP_BIG] candidate dq values
  unsigned* Mlds = (unsigned*)(lval + BM * CAP_BIG);  // [64] running row min
  unsigned* cntl = Mlds + BM;         // [64] append counters
  u16* lidx = (u16*)(cntl + BM);      // [64][CAP_BIG] candidate code idx

  const int t = threadIdx.x;
  const int lane = t & 63;
  const int wid = t >> 6;
  const int wm = wid >> 1, wn = wid & 1;
  const int quad = lane >> 4, lr = lane & 15;
  const int row0 = blockIdx.x * BM;
  // per-lane pre-swizzled source offset within an 8-row group
  const int wrow = lane >> 3;                    // row within group
  const int pl = wrow * C + ((lane & 7) ^ wrow) * 8;  // elem offset

  if (t < BM) {
    z2s[t] = z2np[row0 + t];
    Mlds[t] = 0x7F800000u;  // +inf (positive floats order as uints)
    cntl[t] = 0u;
  }

  // running top-1 per slot (mi*4 + r), cols restricted to this wave's half
  float v1[8], i1f[8];
  #pragma unroll
  for (int s = 0; s < 8; ++s) { v1[s] = 3.4e38f; i1f[s] = 0.f; }

  for (int nt = 0; nt < K / BN; ++nt) {
    const int kc0 = nt * BN;
    __syncthreads();                 // prior n-tile's e2s/list-phase readers done
    if (t < BN) e2s[t] = e2row[kc0 + t];

    f32x4 acc[2][4];
    #pragma unroll
    for (int mi = 0; mi < 2; ++mi)
      #pragma unroll
      for (int ni = 0; ni < 4; ++ni) acc[mi][ni] = (f32x4){0.f, 0.f, 0.f, 0.f};

    for (int ch = 0; ch < C / CH; ++ch) {
      const int c0 = ch * CH;
      __syncthreads();               // prior chunk's frag readers done
      // ---- stage A: 8 groups of 8 rows; wave wid -> groups wid*2, wid*2+1 ----
      #pragma unroll
      for (int i = 0; i < 2; ++i) {
        int grow = (wid * 2 + i) * 8;
        size_t src = (size_t)(row0 + grow) * C + c0 + pl;
        gl_lds16(&zh_g[src], &Ah[grow * CH]);
        gl_lds16(&zl_g[src], &Al[grow * CH]);
      }
      // ---- stage B: 16 groups of 8 rows; wave wid -> groups wid*4..+3 ----
      #pragma unroll
      for (int i = 0; i < 4; ++i) {
        int grow = (wid * 4 + i) * 8;
        size_t src = (size_t)(kc0 + grow) * C + c0 + pl;
        gl_lds16(&eh_g[src], &Bh[grow * CH]);
        gl_lds16(&el_g[src], &Bl[grow * CH]);
      }
      __syncthreads();               // drains vmcnt for global_load_lds
      // ---- compute: 2 k-steps of 32 ----
      #pragma unroll
      for (int s = 0; s < 2; ++s) {
        const int q = s * 4 + quad;
        short8 afh[2], afl[2];
        #pragma unroll
        for (int mi = 0; mi < 2; ++mi) {
          int rowl = wm * 32 + mi * 16 + lr;
          int jp = q ^ (rowl & 7);
          afh[mi] = *(short8*)&Ah[rowl * CH + jp * 8];
          afl[mi] = *(short8*)&Al[rowl * CH + jp * 8];
        }
        #pragma unroll
        for (int ni = 0; ni < 4; ++ni) {
          int rowb = wn * 64 + ni * 16 + lr;
          int jp = q ^ (rowb & 7);
          short8 bh = *(short8*)&Bh[rowb * CH + jp * 8];
          short8 bl = *(short8*)&Bl[rowb * CH + jp * 8];
          #pragma unroll
          for (int mi = 0; mi < 2; ++mi) {
            acc[mi][ni] = __builtin_amdgcn_mfma_f32_16x16x32_bf16(afh[mi], bh, acc[mi][ni], 0, 0, 0);
            acc[mi][ni] = __builtin_amdgcn_mfma_f32_16x16x32_bf16(afh[mi], bl, acc[mi][ni], 0, 0, 0);
            acc[mi][ni] = __builtin_amdgcn_mfma_f32_16x16x32_bf16(afl[mi], bh, acc[mi][ni], 0, 0, 0);
          }
        }
      }
    }
    // ---- scoring phase 1: fold this tile's dq into per-row running min ----
    // dq replicates the reference's rounding: fl(fl(z2+e2) - fl(2g)).
    #pragma unroll
    for (int mi = 0; mi < 2; ++mi)
      #pragma unroll
      for (int r = 0; r < 4; ++r) {
        int row = wm * 32 + mi * 16 + quad * 4 + r;
        float z2r = z2s[row];
        float m4 = 3.4e38f;
        #pragma unroll
        for (int ni = 0; ni < 4; ++ni) {
          int col = wn * 64 + ni * 16 + lr;
          float dq = __fsub_rn(__fadd_rn(z2r, e2s[col]),
                               __fmul_rn(2.f, acc[mi][ni][r]));
          m4 = fminf(m4, dq);
        }
        atomicMin(&Mlds[row], __float_as_uint(m4));
      }
    __syncthreads();
    // ---- scoring phase 2: top-1 track + candidate collect ----
    #pragma unroll
    for (int mi = 0; mi < 2; ++mi)
      #pragma unroll
      for (int r = 0; r < 4; ++r) {
        int row = wm * 32 + mi * 16 + quad * 4 + r;
        float z2r = z2s[row];
        float M = __uint_as_float(Mlds[row]);
        float thr = fmaf(M, TC_FACT, M);
        int slot = mi * 4 + r;
        #pragma unroll
        for (int ni = 0; ni < 4; ++ni) {
          int col = wn * 64 + ni * 16 + lr;
          float dq = __fsub_rn(__fadd_rn(z2r, e2s[col]),
                               __fmul_rn(2.f, acc[mi][ni][r]));
          // strict < keeps first (smallest col) on ties; cols ascend in nt,ni
          if (dq < v1[slot]) { v1[slot] = dq; i1f[slot] = (float)(kc0 + col); }
          if (dq < thr) {
            unsigned p = atomicAdd(&cntl[row], 1u);
            if (p < CAP_BIG) {
              lval[row * CAP_BIG + p] = dq;
              lidx[row * CAP_BIG + p] = (u16)(kc0 + col);
            }
          }
        }
      }
  }
  // ---- butterfly top-1 merge over the 16 col lanes (lr) ----
  #pragma unroll
  for (int off = 1; off < 16; off <<= 1) {
    #pragma unroll
    for (int s = 0; s < 8; ++s) {
      float ov1 = __shfl_xor(v1[s], off);
      float oi1 = __shfl_xor(i1f[s], off);
      bool take = (ov1 < v1[s]) || (ov1 == v1[s] && oi1 < i1f[s]);
      if (take) { v1[s] = ov1; i1f[s] = oi1; }
    }
  }
  // ---- write per-wave (col-half) results to LDS, then merge halves ----
  __syncthreads();   // all waves done with staging buffers / compute / appends
  if (lr == 0) {
    #pragma unroll
    for (int mi = 0; mi < 2; ++mi)
      #pragma unroll
      for (int r = 0; r < 4; ++r) {
        int slot = mi * 4 + r;
        int row = wm * 32 + mi * 16 + quad * 4 + r;   // 0..63
        mv1[wn * BM + row] = v1[slot];
        mi1[wn * BM + row] = i1f[slot];
      }
  }
  __syncthreads();
  if (t < BM) {
    float a1 = mv1[t], ai = mi1[t];
    float c1 = mv1[BM + t], ci = mi1[BM + t];
    bool take = (c1 < a1) || (c1 == a1 && ci < ai);
    float b1 = take ? c1 : a1;
    float bi = take ? ci : ai;
    out_idx[row0 + t] = bi;    // provisional winner (fixup overwrites flagged)
    // filter collected candidates against the final row min
    unsigned raw = cntl[t];
    float tf = fmaf(b1, TF_FACT, b1);
    int c = 0;
    u16 keep[CAP];
    bool ov = raw > (unsigned)CAP_BIG;
    if (!ov) {
      for (unsigned j = 0; j < raw; ++j) {
        if (lval[t * CAP_BIG + j] <= tf) {
          if (c < CAP) keep[c] = lidx[t * CAP_BIG + j];
          ++c;
        }
      }
      if (c > CAP) ov = true;
    }
    if (ov || c > 1) {
      int q = atomicAdd(&qarr[0], 1);
      int cc = ov ? OV : c;
      qarr[1 + q] = (row0 + t) | (cc << 16);
      if (!ov)
        #pragma unroll
        for (int j = 0; j < CAP; ++j)
          cand[(size_t)q * CAP + j] = (j < c) ? keep[j] : (u16)0;
    }
  }
}

// ---------- fixup: exact f64-rounded f32 dots for queued candidates ----------
// One wave per queue entry; <=CAP candidates, each a 64-lane coalesced
// float4 dot + 6-step f64 butterfly, then the reference's rounding sequence
// and lexicographic (d, idx) min == first-index argmin tie-break.
__global__ __launch_bounds__(256)
void fixup_k(const float* __restrict__ z, const float* __restrict__ emb,
             const float* __restrict__ e2np, const float* __restrict__ z2np,
             const int* __restrict__ qarr, const u16* __restrict__ cand,
             float* __restrict__ out_idx) {
  int qcnt = qarr[0];
  if (qcnt > NN) qcnt = NN;
  const int t = threadIdx.x;
  const int lane = t & 63, w = t >> 6;
  for (int q = blockIdx.x * 4 + w; q < qcnt; q += gridDim.x * 4) {
    int e = qarr[1 + q];
    int n = e & 0xffff;
    int c = e >> 16;
    int b = n >> 12, s = n & (SS - 1);
    float z2 = z2np[n];
    // lane's 4 z components (stride-SS gather; L2/L3-hot after prep_z)
    const float* zb = z + (((size_t)b * C) << 12) + s;
    float4 zv;
    zv.x = zb[((size_t)(lane * 4 + 0)) << 12];
    zv.y = zb[((size_t)(lane * 4 + 1)) << 12];
    zv.z = zb[((size_t)(lane * 4 + 2)) << 12];
    zv.w = zb[((size_t)(lane * 4 + 3)) << 12];
    float bestd = 3.4e38f;
    int besti = 0x7fffffff;
    const int nc = (c == OV) ? K : c;
    for (int j = 0; j < nc; ++j) {
      int kk = (c == OV) ? j : (int)cand[(size_t)q * CAP + j];
      const float4 ev = *(const float4*)&emb[(size_t)kk * C + lane * 4];
      double acc = (double)zv.x * (double)ev.x;
      acc = fma((double)zv.y, (double)ev.y, acc);
      acc = fma((double)zv.z, (double)ev.z, acc);
      acc = fma((double)zv.w, (double)ev.w, acc);
      #pragma unroll
      for (int off = 32; off; off >>= 1) acc += __shfl_xor(acc, off);
      float g  = (float)acc;           // correctly-rounded f32 dot
      float t1 = __fadd_rn(z2, e2np[kk]);
      float d  = __fsub_rn(t1, __fmul_rn(2.f, g));
      if (d < bestd || (d == bestd && kk < besti)) { bestd = d; besti = kk; }
    }
    if (lane == 0) out_idx[n] = (float)besti;
  }
}

// ---------- gather via LDS-staged emb rows + loss + histogram ----------
#define GROWS 64
__global__ __launch_bounds__(256)
void gather2_k(const float* __restrict__ z, const float* __restrict__ emb,
               float* __restrict__ out, float* __restrict__ ws,
               float* __restrict__ counts) {
  __shared__ float eb[GROWS * 257];
  __shared__ int idxs[GROWS];
  __shared__ float sc[4];
  const int t = threadIdx.x;
  const int n0 = blockIdx.x * GROWS;
  const int b = n0 >> 12;
  const int s0 = n0 & (SS - 1);
  if (t < GROWS) {
    int id = (int)out[OUT_IDX + n0 + t];
    idxs[t] = id;
    atomicAdd(&counts[id], 1.0f);
  }
  __syncthreads();
  #pragma unroll
  for (int i = 0; i < 16; ++i) {
    int q = i * 256 + t;
    int row = q >> 6, c4 = q & 63;
    float4 v = *(const float4*)&emb[(size_t)idxs[row] * C + c4 * 4];
    int base = row * 257 + c4 * 4;
    eb[base + 0] = v.x; eb[base + 1] = v.y;
    eb[base + 2] = v.z; eb[base + 3] = v.w;
  }
  __syncthreads();
  const int sl = t & 63, cg = t >> 6;
  const float* zb = z + (size_t)b * C * SS + s0 + sl;
  float* ob = out + (size_t)b * C * SS + s0 + sl;
  float l = 0.f;
  #pragma unroll 4
  for (int i = 0; i < 64; ++i) {
    int c = cg * 64 + i;
    float q = eb[sl * 257 + c];
    float zv = zb[(size_t)c * SS];
    float d = q - zv;
    l += d * d;
    ob[(size_t)c * SS] = q;
  }
  #pragma unroll
  for (int off = 32; off; off >>= 1) l += __shfl_down(l, off);
  int lane = t & 63, w = t >> 6;
  if (lane == 0) sc[w] = l;
  __syncthreads();
  if (t == 0)
    atomicAdd(&ws[WS_LOSS], sc[0] + sc[1] + sc[2] + sc[3]);
}

// ---------- finalize scalars ----------
__global__ void finalize_k(const float* __restrict__ ws, float* __restrict__ out) {
  __shared__ float sc[8];
  int t = threadIdx.x;
  float ent = 0.f;
  #pragma unroll
  for (int k = t; k < K; k += 256) {
    float em = ws[WS_CNT + k] * (1.0f / NN);
    ent += em * logf(em + 1e-10f);
  }
  float zd = ws[WS_ZSUM + t] * ws[WS_ESUM + t];
  #pragma unroll
  for (int off = 32; off; off >>= 1) {
    ent += __shfl_down(ent, off);
    zd  += __shfl_down(zd, off);
  }
  int lane = t & 63, w = t >> 6;
  if (lane == 0) { sc[w] = ent; sc[4 + w] = zd; }
  __syncthreads();
  if (t == 0) {
    ent = sc[0] + sc[1] + sc[2] + sc[3];
    zd  = sc[4] + sc[5] + sc[6] + sc[7];
    out[OUT_LOSS] = 1.25f * ws[WS_LOSS] * (1.0f / ZQ_ELEMS);
    out[OUT_PERP] = expf(-ent);
    out[OUT_MD]   = ws[WS_SZ2] * (1.0f / NN) + ws[WS_SE2] * (1.0f / K)
                  - 2.0f * zd * (1.0f / ((float)NN * (float)K));
  }
}

extern "C" void kernel_launch(void* const* d_in, const int* in_sizes, int n_in,
                              void* d_out, int out_size, void* d_ws, size_t ws_size,
                              hipStream_t stream) {
  const float* z   = (const float*)d_in[0];
  const float* emb = (const float*)d_in[1];
  float* out = (float*)d_out;
  float* ws  = (float*)d_ws;
  int* qarr = (int*)(ws + WS_FLG);
  u16* cand = (u16*)(ws + WS_CAND);
  u16* eh_g = (u16*)(ws + WS_EH);
  u16* el_g = (u16*)(ws + WS_EL);
  // zh/zl live in d_out's zq region; overwritten by gather2_k at the end.
  u16* zh_g = (u16*)d_out;
  u16* zl_g = zh_g + (size_t)ZQ_ELEMS;
  (void)in_sizes; (void)n_in; (void)out_size; (void)ws_size;

  hipMemsetAsync(d_ws, 0, WS_E2R * sizeof(float), stream);
  hipMemsetAsync(ws + WS_FLG, 0, sizeof(int), stream);
  emb_prep_k<<<64, 256, 0, stream>>>(emb, ws, eh_g, el_g);
  prep_z_k<<<NN / MROWS, 256, 0, stream>>>(z, ws, zh_g, zl_g);
  size_t lds = (size_t)(2 * BM * CH + 2 * BN * CH) * sizeof(u16)
             + (size_t)(BN + 4 * BM + BM + BM * CAP_BIG) * sizeof(float)
             + (size_t)(2 * BM) * sizeof(unsigned)
             + (size_t)(BM * CAP_BIG) * sizeof(u16);
  vq_mfma_k<<<NN / BM, 256, lds, stream>>>(zh_g, zl_g, eh_g, el_g,
                                           ws + WS_E2R, ws + WS_Z2N,
                                           out + OUT_IDX, qarr, cand);
  fixup_k<<<2048, 256, 0, stream>>>(z, emb, ws + WS_E2R, ws + WS_Z2N,
                                    qarr, cand, out + OUT_IDX);
  gather2_k<<<NN / GROWS, 256, 0, stream>>>(z, emb, out, ws, ws + WS_CNT);
  finalize_k<<<1, 256, 0, stream>>>(ws, out);
}